// Round 1
// baseline (3377.654 us; speedup 1.0000x reference)
//
#include <hip/hip_runtime.h>
#include <math.h>

#define BSZ 8
#define LEN 3072
#define DM 1024
#define TOPK 8

// ---------------------------------------------------------------------------
// f32 tiled GEMM: C[M,N] = A[M,K] * B[K,N] (+ bias[N]), all row-major.
// 128x128 block tile, BK=16, 256 threads, 8x8 per-thread micro-tile.
// ---------------------------------------------------------------------------
#define GBM 128
#define GBN 128
#define GBK 16

__global__ __launch_bounds__(256) void gemm_f32(const float* __restrict__ A,
    const float* __restrict__ B, const float* __restrict__ bias,
    float* __restrict__ C, int M, int N, int K)
{
    __shared__ float As[GBK][GBM];
    __shared__ float Bs[GBK][GBN];
    const int tid = threadIdx.x;
    const int tx = tid & 15, ty = tid >> 4;
    const size_t m0 = (size_t)blockIdx.y * GBM;
    const size_t n0 = (size_t)blockIdx.x * GBN;
    const int arow = tid >> 2, acol = (tid & 3) << 2;   // A tile: 128 rows x 16 cols
    const int brow = tid >> 5, bcol = (tid & 31) << 2;  // B tile: 16 rows x 128 cols

    float acc[8][8];
#pragma unroll
    for (int i = 0; i < 8; i++)
#pragma unroll
        for (int j = 0; j < 8; j++) acc[i][j] = 0.f;

    const float* Ap0 = A + (m0 + arow) * (size_t)K + acol;
    const float* Ap1 = A + (m0 + arow + 64) * (size_t)K + acol;
    const float* Bp0 = B + (size_t)brow * N + n0 + bcol;
    const float* Bp1 = B + (size_t)(brow + 8) * N + n0 + bcol;

    for (int k0 = 0; k0 < K; k0 += GBK) {
        float4 a0 = *(const float4*)(Ap0 + k0);
        float4 a1 = *(const float4*)(Ap1 + k0);
        float4 b0 = *(const float4*)(Bp0 + (size_t)k0 * N);
        float4 b1 = *(const float4*)(Bp1 + (size_t)k0 * N);
        __syncthreads();   // all threads done reading LDS from previous iter
        As[acol + 0][arow] = a0.x; As[acol + 1][arow] = a0.y;
        As[acol + 2][arow] = a0.z; As[acol + 3][arow] = a0.w;
        As[acol + 0][arow + 64] = a1.x; As[acol + 1][arow + 64] = a1.y;
        As[acol + 2][arow + 64] = a1.z; As[acol + 3][arow + 64] = a1.w;
        *(float4*)&Bs[brow][bcol] = b0;
        *(float4*)&Bs[brow + 8][bcol] = b1;
        __syncthreads();
#pragma unroll
        for (int kk = 0; kk < GBK; kk++) {
            float av[8], bv[8];
            *(float4*)&av[0] = *(const float4*)&As[kk][ty * 8];
            *(float4*)&av[4] = *(const float4*)&As[kk][ty * 8 + 4];
            *(float4*)&bv[0] = *(const float4*)&Bs[kk][tx * 8];
            *(float4*)&bv[4] = *(const float4*)&Bs[kk][tx * 8 + 4];
#pragma unroll
            for (int i = 0; i < 8; i++)
#pragma unroll
                for (int j = 0; j < 8; j++)
                    acc[i][j] = fmaf(av[i], bv[j], acc[i][j]);
        }
    }
#pragma unroll
    for (int i = 0; i < 8; i++) {
        size_t row = m0 + (size_t)(ty * 8 + i);
        float* Cp = C + row * N + n0 + tx * 8;
#pragma unroll
        for (int j = 0; j < 8; j++) {
            float v = acc[i][j];
            if (bias) v += bias[n0 + tx * 8 + j];
            Cp[j] = v;
        }
    }
}

// ---------------------------------------------------------------------------
// 1024x1024 f32 transpose (for Wq -> WqT)
// ---------------------------------------------------------------------------
__global__ __launch_bounds__(256) void transpose_1024(const float* __restrict__ in,
                                                      float* __restrict__ out)
{
    __shared__ float tile[32][33];
    int bx = blockIdx.x & 31, by = blockIdx.x >> 5;
    int tx = threadIdx.x & 31, tq = threadIdx.x >> 5;
#pragma unroll
    for (int r = 0; r < 4; r++) {
        int y = by * 32 + tq * 4 + r;
        tile[tq * 4 + r][tx] = in[(size_t)y * 1024 + bx * 32 + tx];
    }
    __syncthreads();
#pragma unroll
    for (int r = 0; r < 4; r++) {
        int y = bx * 32 + tq * 4 + r;
        out[(size_t)y * 1024 + by * 32 + tx] = tile[tx][tq * 4 + r];
    }
}

// bz[j] = sum_d bk[d] * WqT[d,j]
__global__ __launch_bounds__(256) void bz_kernel(const float* __restrict__ bk,
    const float* __restrict__ WqT, float* __restrict__ bz)
{
    int j = blockIdx.x * 256 + threadIdx.x;
    float s = 0.f;
    for (int d = 0; d < 1024; d++) s = fmaf(bk[d], WqT[(size_t)d * 1024 + j], s);
    bz[j] = s;
}

__global__ void zero_f32(float* __restrict__ p, int n)
{
    int i = blockIdx.x * 256 + threadIdx.x;
    if (i < n) p[i] = 0.f;
}

// ---------------------------------------------------------------------------
// 3072-point complex FFT in LDS: 3 x 1024 Stockham radix-2 + radix-3 combine.
// Input in (re0,im0), deinterleaved as [t%3][t/3]; output natural order in
// (re1,im1). Block must have 256 threads; ends with __syncthreads().
// ---------------------------------------------------------------------------
__device__ __forceinline__ void fft3072(float* re0, float* im0, float* re1, float* im1,
                                        const float* twR, const float* twI,
                                        const float* t3R, const float* t3I, int tid)
{
    float* srcR = re0; float* srcI = im0;
    float* dstR = re1; float* dstI = im1;
    for (int s = 0; s < 10; s++) {
        int st = 1 << s;
        int m = 512 >> s;
        for (int w = tid; w < 1536; w += 256) {
            int sub = w >> 9, idx = w & 511;
            int p = idx >> s;
            int q = idx & (st - 1);
            int base = sub << 10;
            int ia = base + q + st * p;
            int ib = ia + st * m;
            float aR = srcR[ia], aI = srcI[ia];
            float bR = srcR[ib], bI = srcI[ib];
            int ti = p << s;
            float wR = twR[ti], wI = twI[ti];
            int io = base + q + st * 2 * p;
            dstR[io] = aR + bR; dstI[io] = aI + bI;
            float dR = aR - bR, dI = aI - bI;
            dstR[io + st] = dR * wR - dI * wI;
            dstI[io + st] = dR * wI + dI * wR;
        }
        __syncthreads();
        float* t;
        t = srcR; srcR = dstR; dstR = t;
        t = srcI; srcI = dstI; dstI = t;
    }
    // after 10 stages data is back in re0/im0 (== srcR/srcI); combine -> re1/im1
    const float OMR = -0.5f, OMI = -0.86602540378443864676f; // e^{-2pi i/3}
    for (int k2 = tid; k2 < 1024; k2 += 256) {
        float y0R = srcR[k2],        y0I = srcI[k2];
        float y1R = srcR[1024 + k2], y1I = srcI[1024 + k2];
        float y2R = srcR[2048 + k2], y2I = srcI[2048 + k2];
        float w1R = t3R[k2], w1I = t3I[k2];
        float w2R = w1R * w1R - w1I * w1I;
        float w2I = 2.f * w1R * w1I;
        float u1R = y1R * w1R - y1I * w1I, u1I = y1R * w1I + y1I * w1R;
        float u2R = y2R * w2R - y2I * w2I, u2I = y2R * w2I + y2I * w2R;
        dstR[k2] = y0R + u1R + u2R;
        dstI[k2] = y0I + u1I + u2I;
        dstR[1024 + k2] = y0R + (OMR * u1R - OMI * u1I) + (OMR * u2R + OMI * u2I);
        dstI[1024 + k2] = y0I + (OMR * u1I + OMI * u1R) + (OMR * u2I - OMI * u2R);
        dstR[2048 + k2] = y0R + (OMR * u1R + OMI * u1I) + (OMR * u2R - OMI * u2I);
        dstI[2048 + k2] = y0I + (OMR * u1I - OMI * u1R) + (OMR * u2I + OMI * u2R);
    }
    __syncthreads();
}

// ---------------------------------------------------------------------------
// Per (batch, 16-channel group): pack w = xq + i*z, FFT, extract
// P[f] = Qf * conj(Zf), accumulate over channels in regs, atomicAdd into S.
// ---------------------------------------------------------------------------
__global__ __launch_bounds__(256) void fft_corr(const float* __restrict__ xq,
    const float* __restrict__ z, float* __restrict__ S)
{
    __shared__ float re0[3072], im0[3072], re1[3072], im1[3072];
    __shared__ float twR[512], twI[512], t3R[1024], t3I[1024];
    const int tid = threadIdx.x;
    const int b = blockIdx.x >> 6;
    const int c0 = (blockIdx.x & 63) << 4;
    const float TWO_PI = 6.28318530717958647692f;
    for (int j = tid; j < 512; j += 256) {
        float s, c; sincosf(-TWO_PI * (float)j / 1024.f, &s, &c);
        twR[j] = c; twI[j] = s;
    }
    for (int j = tid; j < 1024; j += 256) {
        float s, c; sincosf(-TWO_PI * (float)j / 3072.f, &s, &c);
        t3R[j] = c; t3I[j] = s;
    }
    float pR[12], pI[12];
#pragma unroll
    for (int j = 0; j < 12; j++) { pR[j] = 0.f; pI[j] = 0.f; }
    __syncthreads();

    for (int ci = 0; ci < 16; ci++) {
        int c = c0 + ci;
        const float* qp = xq + (size_t)b * LEN * DM + c;
        const float* zp = z  + (size_t)b * LEN * DM + c;
        for (int t = tid; t < 3072; t += 256) {
            float qv = qp[(size_t)t * DM];
            float zv = zp[(size_t)t * DM];
            int t1 = t % 3, t2 = t / 3;
            re0[t1 * 1024 + t2] = qv;
            im0[t1 * 1024 + t2] = zv;
        }
        __syncthreads();
        fft3072(re0, im0, re1, im1, twR, twI, t3R, t3I, tid);
        // W[f] in re1/im1 (natural order). Extract Qf, Zf, accumulate P.
#pragma unroll
        for (int j = 0; j < 12; j++) {
            int f = tid + (j << 8);
            int fc = (f == 0) ? 0 : 3072 - f;
            float WfR = re1[f],  WfI = im1[f];
            float WcR = re1[fc], WcI = -im1[fc];
            float qR = 0.5f * (WfR + WcR), qI = 0.5f * (WfI + WcI);
            float dR = WfR - WcR, dI = WfI - WcI;
            float zR = 0.5f * dI, zI = -0.5f * dR;
            pR[j] += qR * zR + qI * zI;
            pI[j] += qI * zR - qR * zI;
        }
        __syncthreads();
    }
    float* Sb = S + (size_t)b * 3072 * 2;
#pragma unroll
    for (int j = 0; j < 12; j++) {
        int f = tid + (j << 8);
        atomicAdd(&Sb[f * 2 + 0], pR[j]);
        atomicAdd(&Sb[f * 2 + 1], pI[j]);
    }
}

// mean_value[b,t] = Re(FFT(conj(S[b]))[t]) / (3072*1024)
__global__ __launch_bounds__(256) void ifft_mean(const float* __restrict__ S,
                                                 float* __restrict__ mv)
{
    __shared__ float re0[3072], im0[3072], re1[3072], im1[3072];
    __shared__ float twR[512], twI[512], t3R[1024], t3I[1024];
    const int tid = threadIdx.x;
    const int b = blockIdx.x;
    const float TWO_PI = 6.28318530717958647692f;
    for (int j = tid; j < 512; j += 256) {
        float s, c; sincosf(-TWO_PI * (float)j / 1024.f, &s, &c);
        twR[j] = c; twI[j] = s;
    }
    for (int j = tid; j < 1024; j += 256) {
        float s, c; sincosf(-TWO_PI * (float)j / 3072.f, &s, &c);
        t3R[j] = c; t3I[j] = s;
    }
    __syncthreads();
    for (int t = tid; t < 3072; t += 256) {
        float sR = S[((size_t)b * 3072 + t) * 2 + 0];
        float sI = S[((size_t)b * 3072 + t) * 2 + 1];
        int t1 = t % 3, t2 = t / 3;
        re0[t1 * 1024 + t2] = sR;
        im0[t1 * 1024 + t2] = -sI;
    }
    __syncthreads();
    fft3072(re0, im0, re1, im1, twR, twI, t3R, t3I, tid);
    const float scale = 1.f / (3072.f * 1024.f);
    for (int t = tid; t < 3072; t += 256)
        mv[(size_t)b * 3072 + t] = re1[t] * scale;
}

// ---------------------------------------------------------------------------
// top-8 (value,index) per batch, then softmax over the 8 values.
// ---------------------------------------------------------------------------
__global__ __launch_bounds__(256) void topk_softmax(const float* __restrict__ mv,
    float* __restrict__ wout, int* __restrict__ dout)
{
    const int b = blockIdx.x, tid = threadIdx.x;
    __shared__ float v[3072];
    __shared__ float rv[256];
    __shared__ int   ri[256];
    __shared__ float topv[TOPK];
    __shared__ int   topi[TOPK];
    for (int t = tid; t < 3072; t += 256) v[t] = mv[(size_t)b * 3072 + t];
    __syncthreads();
    for (int it = 0; it < TOPK; it++) {
        float best = -3.0e38f; int bi = 0;
        for (int t = tid; t < 3072; t += 256) {
            float x = v[t];
            if (x > best) { best = x; bi = t; }
        }
        rv[tid] = best; ri[tid] = bi;
        __syncthreads();
        for (int off = 128; off > 0; off >>= 1) {
            if (tid < off) {
                float ov = rv[tid + off]; int oi = ri[tid + off];
                if (ov > rv[tid] || (ov == rv[tid] && oi < ri[tid])) {
                    rv[tid] = ov; ri[tid] = oi;
                }
            }
            __syncthreads();
        }
        if (tid == 0) { topv[it] = rv[0]; topi[it] = ri[0]; v[ri[0]] = -3.0e38f; }
        __syncthreads();
    }
    if (tid == 0) {
        float m = topv[0];
        float e[TOPK]; float ssum = 0.f;
        for (int i = 0; i < TOPK; i++) { e[i] = expf(topv[i] - m); ssum += e[i]; }
        for (int i = 0; i < TOPK; i++) {
            wout[b * TOPK + i] = e[i] / ssum;
            dout[b * TOPK + i] = topi[i];
        }
    }
}

// agg[b,t,:] = sum_i w[b,i] * V[b,(t+d[b,i])%L,:]
__global__ __launch_bounds__(256) void agg_kernel(const float* __restrict__ V,
    const float* __restrict__ w, const int* __restrict__ d, float* __restrict__ agg)
{
    size_t gid = (size_t)blockIdx.x * 256 + threadIdx.x;  // float4 index
    int c4 = (int)(gid & 255);
    size_t rest = gid >> 8;
    int t = (int)(rest % LEN);
    int b = (int)(rest / LEN);
    const float4* V4 = (const float4*)V;
    float4 acc = make_float4(0.f, 0.f, 0.f, 0.f);
#pragma unroll
    for (int i = 0; i < TOPK; i++) {
        float wi = w[b * TOPK + i];
        int r = t + d[b * TOPK + i];
        if (r >= LEN) r -= LEN;
        float4 val = V4[((size_t)b * LEN + r) * 256 + c4];
        acc.x = fmaf(wi, val.x, acc.x);
        acc.y = fmaf(wi, val.y, acc.y);
        acc.z = fmaf(wi, val.z, acc.z);
        acc.w = fmaf(wi, val.w, acc.w);
    }
    ((float4*)agg)[gid] = acc;
}

// ---------------------------------------------------------------------------
extern "C" void kernel_launch(void* const* d_in, const int* in_sizes, int n_in,
                              void* d_out, int out_size, void* d_ws, size_t ws_size,
                              hipStream_t stream)
{
    const float* queries = (const float*)d_in[0];
    const float* keys    = (const float*)d_in[1];
    const float* values  = (const float*)d_in[2];
    const float* Wq = (const float*)d_in[3];
    const float* bq = (const float*)d_in[4]; (void)bq; // constant-in-tau term: softmax/topk invariant
    const float* Wk = (const float*)d_in[5];
    const float* bk = (const float*)d_in[6];
    const float* Wv = (const float*)d_in[7];
    const float* bv = (const float*)d_in[8];
    const float* Wo = (const float*)d_in[9];
    const float* bo = (const float*)d_in[10];
    float* out = (float*)d_out;

    char* ws = (char*)d_ws;
    size_t off = 0;
    auto alloc = [&](size_t bytes) -> char* {
        char* p = ws + off;
        off += (bytes + 255) & ~(size_t)255;
        return p;
    };
    float* WqT  = (float*)alloc((size_t)1024 * 1024 * 4);
    float* Amat = (float*)alloc((size_t)1024 * 1024 * 4);
    float* bz   = (float*)alloc(1024 * 4);
    float* S    = (float*)alloc((size_t)BSZ * 3072 * 2 * 4);
    float* mv   = (float*)alloc((size_t)BSZ * 3072 * 4);
    float* wsm  = (float*)alloc(BSZ * TOPK * 4);
    int*   dly  = (int*)alloc(BSZ * TOPK * 4);
    float* zbuf = (float*)alloc((size_t)BSZ * LEN * DM * 4);  // later reused as agg
    float* Vbuf = (float*)alloc((size_t)BSZ * LEN * DM * 4);

    const int BL = BSZ * LEN; // 24576

    // 1. WqT = Wq^T
    transpose_1024<<<1024, 256, 0, stream>>>(Wq, WqT);
    // 2. Amat = Wk @ WqT   (= Wk Wq^T)
    gemm_f32<<<dim3(8, 8), 256, 0, stream>>>(Wk, WqT, nullptr, Amat, 1024, 1024, 1024);
    // 3. bz = bk @ WqT
    bz_kernel<<<4, 256, 0, stream>>>(bk, WqT, bz);
    // 4. z = keys @ Amat + bz      [BL, 1024]
    gemm_f32<<<dim3(8, 192), 256, 0, stream>>>(keys, Amat, bz, zbuf, BL, 1024, 1024);
    // 5. V = values @ Wv + bv      [BL, 1024]
    gemm_f32<<<dim3(8, 192), 256, 0, stream>>>(values, Wv, bv, Vbuf, BL, 1024, 1024);
    // 6. S = 0  (ws is poisoned before every launch)
    zero_f32<<<(BSZ * 3072 * 2 + 255) / 256, 256, 0, stream>>>(S, BSZ * 3072 * 2);
    // 7. correlation spectrum: S[b,f] = sum_c Qf * conj(Zf)
    fft_corr<<<BSZ * 64, 256, 0, stream>>>(queries, zbuf, S);
    // 8. mean_value = irfft(S)/1024
    ifft_mean<<<BSZ, 256, 0, stream>>>(S, mv);
    // 9. top-8 + softmax
    topk_softmax<<<BSZ, 256, 0, stream>>>(mv, wsm, dly);
    // 10. time-delay aggregation (reuse zbuf as agg; z is dead after step 7)
    agg_kernel<<<(BSZ * LEN * (DM / 4)) / 256, 256, 0, stream>>>(Vbuf, wsm, dly, zbuf);
    // 11. out = agg @ Wo + bo
    gemm_f32<<<dim3(8, 192), 256, 0, stream>>>(zbuf, Wo, bo, out, BL, 1024, 1024);
}

// Round 2
// 1531.195 us; speedup vs baseline: 2.2059x; 2.2059x over previous
//
#include <hip/hip_runtime.h>
#include <math.h>

#define BSZ 8
#define LEN 3072
#define DM 1024
#define TOPK 8

typedef __attribute__((ext_vector_type(8))) short short8;
typedef __attribute__((ext_vector_type(4))) float f32x4;

__device__ __forceinline__ unsigned short f2bf(float x) {
    unsigned int u = __builtin_bit_cast(unsigned int, x);
    u += 0x7fffu + ((u >> 16) & 1u);   // RNE
    return (unsigned short)(u >> 16);
}
__device__ __forceinline__ float bf2f(unsigned short h) {
    unsigned int u = ((unsigned int)h) << 16;
    return __builtin_bit_cast(float, u);
}
__device__ __forceinline__ void gl_lds16(const void* g, void* l) {
    __builtin_amdgcn_global_load_lds(
        (const __attribute__((address_space(1))) unsigned int*)g,
        (__attribute__((address_space(3))) unsigned int*)l, 16, 0, 0);
}

// ---------------------------------------------------------------------------
// f32 tiled GEMM: C[M,N] = A[M,K] * B[K,N] (+ bias[N]), all row-major.
// tmode==1: store batch-transposed: C[b][n][t] with m = b*LEN + t (M mult of 128,
// 128 | LEN). Used for the selection-critical z path (stays f32 for accuracy).
// ---------------------------------------------------------------------------
#define GBM 128
#define GBN 128
#define GBK 16

__global__ __launch_bounds__(256) void gemm_f32(const float* __restrict__ A,
    const float* __restrict__ B, const float* __restrict__ bias,
    float* __restrict__ C, int M, int N, int K, int tmode)
{
    __shared__ float As[GBK][GBM];
    __shared__ float Bs[GBK][GBN];
    const int tid = threadIdx.x;
    const int tx = tid & 15, ty = tid >> 4;
    const size_t m0 = (size_t)blockIdx.y * GBM;
    const size_t n0 = (size_t)blockIdx.x * GBN;
    const int arow = tid >> 2, acol = (tid & 3) << 2;
    const int brow = tid >> 5, bcol = (tid & 31) << 2;

    float acc[8][8];
#pragma unroll
    for (int i = 0; i < 8; i++)
#pragma unroll
        for (int j = 0; j < 8; j++) acc[i][j] = 0.f;

    const float* Ap0 = A + (m0 + arow) * (size_t)K + acol;
    const float* Ap1 = A + (m0 + arow + 64) * (size_t)K + acol;
    const float* Bp0 = B + (size_t)brow * N + n0 + bcol;
    const float* Bp1 = B + (size_t)(brow + 8) * N + n0 + bcol;

    for (int k0 = 0; k0 < K; k0 += GBK) {
        float4 a0 = *(const float4*)(Ap0 + k0);
        float4 a1 = *(const float4*)(Ap1 + k0);
        float4 b0 = *(const float4*)(Bp0 + (size_t)k0 * N);
        float4 b1 = *(const float4*)(Bp1 + (size_t)k0 * N);
        __syncthreads();
        As[acol + 0][arow] = a0.x; As[acol + 1][arow] = a0.y;
        As[acol + 2][arow] = a0.z; As[acol + 3][arow] = a0.w;
        As[acol + 0][arow + 64] = a1.x; As[acol + 1][arow + 64] = a1.y;
        As[acol + 2][arow + 64] = a1.z; As[acol + 3][arow + 64] = a1.w;
        *(float4*)&Bs[brow][bcol] = b0;
        *(float4*)&Bs[brow + 8][bcol] = b1;
        __syncthreads();
#pragma unroll
        for (int kk = 0; kk < GBK; kk++) {
            float av[8], bv[8];
            *(float4*)&av[0] = *(const float4*)&As[kk][ty * 8];
            *(float4*)&av[4] = *(const float4*)&As[kk][ty * 8 + 4];
            *(float4*)&bv[0] = *(const float4*)&Bs[kk][tx * 8];
            *(float4*)&bv[4] = *(const float4*)&Bs[kk][tx * 8 + 4];
#pragma unroll
            for (int i = 0; i < 8; i++)
#pragma unroll
                for (int j = 0; j < 8; j++)
                    acc[i][j] = fmaf(av[i], bv[j], acc[i][j]);
        }
    }
    if (tmode == 0) {
#pragma unroll
        for (int i = 0; i < 8; i++) {
            size_t row = m0 + (size_t)(ty * 8 + i);
            float* Cp = C + row * N + n0 + tx * 8;
#pragma unroll
            for (int j = 0; j < 8; j++) {
                float v = acc[i][j];
                if (bias) v += bias[n0 + tx * 8 + j];
                Cp[j] = v;
            }
        }
    } else {
        int b = (int)(m0 / LEN);
        int t0 = (int)(m0 - (size_t)b * LEN) + ty * 8;
#pragma unroll
        for (int j = 0; j < 8; j++) {
            int n = (int)n0 + tx * 8 + j;
            float bb = bias ? bias[n] : 0.f;
            float* zp = C + ((size_t)b * DM + n) * LEN + t0;
#pragma unroll
            for (int i = 0; i < 8; i++) zp[i] = acc[i][j] + bb;
        }
    }
}

// ---------------------------------------------------------------------------
// bf16 MFMA GEMM (m97 structure): C[M,N] = A[M,K] * Bt[N,K]^T + bias.
// 128x128 tile, BK=32, 256 threads (4 waves, 2x2), 16x16x32 MFMA,
// global_load_lds width=16. cmode: 0 -> f32 C, 1 -> bf16 C.
// ---------------------------------------------------------------------------
__global__ __launch_bounds__(256) void gemm_bf16(const unsigned short* __restrict__ A,
    const unsigned short* __restrict__ Bt, const float* __restrict__ bias,
    void* __restrict__ C, int M, int N, int K, int cmode)
{
    __shared__ unsigned short As[128 * 32];
    __shared__ unsigned short Bs[128 * 32];
    const int tid = threadIdx.x;
    const int lane = tid & 63;
    const int wv = tid >> 6;
    const int wm = wv >> 1, wn = wv & 1;
    const int l16 = lane & 15, quad = lane >> 4;
    const size_t m0 = (size_t)blockIdx.y * 128;
    const size_t n0 = (size_t)blockIdx.x * 128;

    // staging segments: s in [0,512): row = s>>2 (0..127), col8 = s&3
    const int s0 = tid, s1 = tid + 256;
    const unsigned short* gA0 = A + (m0 + (s0 >> 2)) * (size_t)K + (s0 & 3) * 8;
    const unsigned short* gA1 = A + (m0 + (s1 >> 2)) * (size_t)K + (s1 & 3) * 8;
    const unsigned short* gB0 = Bt + (n0 + (s0 >> 2)) * (size_t)K + (s0 & 3) * 8;
    const unsigned short* gB1 = Bt + (n0 + (s1 >> 2)) * (size_t)K + (s1 & 3) * 8;
    unsigned short* lA0 = &As[s0 * 8];
    unsigned short* lA1 = &As[s1 * 8];
    unsigned short* lB0 = &Bs[s0 * 8];
    unsigned short* lB1 = &Bs[s1 * 8];

    f32x4 acc[4][4];
#pragma unroll
    for (int i = 0; i < 4; i++)
#pragma unroll
        for (int j = 0; j < 4; j++) acc[i][j] = (f32x4){0.f, 0.f, 0.f, 0.f};

    for (int k0 = 0; k0 < K; k0 += 32) {
        __syncthreads();   // previous iter's ds_reads done
        gl_lds16(gA0 + k0, lA0);
        gl_lds16(gA1 + k0, lA1);
        gl_lds16(gB0 + k0, lB0);
        gl_lds16(gB1 + k0, lB1);
        __syncthreads();   // drains vmcnt (global_load_lds) + barrier
        short8 af[4], bf[4];
#pragma unroll
        for (int mi = 0; mi < 4; mi++)
            af[mi] = *(const short8*)&As[(wm * 64 + mi * 16 + l16) * 32 + quad * 8];
#pragma unroll
        for (int ni = 0; ni < 4; ni++)
            bf[ni] = *(const short8*)&Bs[(wn * 64 + ni * 16 + l16) * 32 + quad * 8];
#pragma unroll
        for (int mi = 0; mi < 4; mi++)
#pragma unroll
            for (int ni = 0; ni < 4; ni++)
                acc[mi][ni] = __builtin_amdgcn_mfma_f32_16x16x32_bf16(
                    af[mi], bf[ni], acc[mi][ni], 0, 0, 0);
    }

#pragma unroll
    for (int mi = 0; mi < 4; mi++) {
#pragma unroll
        for (int ni = 0; ni < 4; ni++) {
            int gm = (int)m0 + wm * 64 + mi * 16 + quad * 4;
            int gn = (int)n0 + wn * 64 + ni * 16 + l16;
            float bb = bias ? bias[gn] : 0.f;
#pragma unroll
            for (int r = 0; r < 4; r++) {
                float v = acc[mi][ni][r] + bb;
                if (cmode == 0)
                    ((float*)C)[(size_t)(gm + r) * N + gn] = v;
                else
                    ((unsigned short*)C)[(size_t)(gm + r) * N + gn] = f2bf(v);
            }
        }
    }
}

// ---------------------------------------------------------------------------
// [B, L, D] f32 -> [B, D, L] f32 transpose (for queries)
// ---------------------------------------------------------------------------
__global__ __launch_bounds__(256) void transpose_bld(const float* __restrict__ in,
                                                     float* __restrict__ out)
{
    __shared__ float tile[32][33];
    int b = blockIdx.z;
    int d0 = blockIdx.x * 32, t0 = blockIdx.y * 32;
    int tx = threadIdx.x & 31, ty = threadIdx.x >> 5;   // 32 x 8
    const float* ip = in + (size_t)b * LEN * DM;
    float* op = out + (size_t)b * DM * LEN;
#pragma unroll
    for (int r = 0; r < 4; r++)
        tile[ty * 4 + r][tx] = ip[(size_t)(t0 + ty * 4 + r) * DM + d0 + tx];
    __syncthreads();
#pragma unroll
    for (int r = 0; r < 4; r++)
        op[(size_t)(d0 + ty * 4 + r) * LEN + t0 + tx] = tile[tx][ty * 4 + r];
}

// 1024x1024 f32 transpose (Wq -> WqT)
__global__ __launch_bounds__(256) void transpose_1024(const float* __restrict__ in,
                                                      float* __restrict__ out)
{
    __shared__ float tile[32][33];
    int bx = blockIdx.x & 31, by = blockIdx.x >> 5;
    int tx = threadIdx.x & 31, tq = threadIdx.x >> 5;
#pragma unroll
    for (int r = 0; r < 4; r++)
        tile[tq * 4 + r][tx] = in[(size_t)(by * 32 + tq * 4 + r) * 1024 + bx * 32 + tx];
    __syncthreads();
#pragma unroll
    for (int r = 0; r < 4; r++)
        out[(size_t)(bx * 32 + tq * 4 + r) * 1024 + by * 32 + tx] = tile[tx][tq * 4 + r];
}

// 1024x1024 f32 W[K][N] -> bf16 WT[N][K]
__global__ __launch_bounds__(256) void transpose_w_bf16(const float* __restrict__ in,
                                                        unsigned short* __restrict__ out)
{
    __shared__ float tile[32][33];
    int bx = blockIdx.x & 31, by = blockIdx.x >> 5;   // bx: n-tile? use bx=cols(n), by=rows(k)
    int tx = threadIdx.x & 31, tq = threadIdx.x >> 5;
#pragma unroll
    for (int r = 0; r < 4; r++)
        tile[tq * 4 + r][tx] = in[(size_t)(by * 32 + tq * 4 + r) * 1024 + bx * 32 + tx];
    __syncthreads();
#pragma unroll
    for (int r = 0; r < 4; r++)
        out[(size_t)(bx * 32 + tq * 4 + r) * 1024 + by * 32 + tx] = f2bf(tile[tx][tq * 4 + r]);
}

// f32 -> bf16 elementwise (n multiple of 4)
__global__ __launch_bounds__(256) void conv_bf16(const float* __restrict__ in,
                                                 unsigned short* __restrict__ out, size_t n)
{
    size_t i = ((size_t)blockIdx.x * 256 + threadIdx.x) * 4;
    if (i >= n) return;
    float4 v = *(const float4*)(in + i);
    ushort4 o;
    o.x = f2bf(v.x); o.y = f2bf(v.y); o.z = f2bf(v.z); o.w = f2bf(v.w);
    *(ushort4*)(out + i) = o;
}

// bz[j] = sum_d bk[d] * WqT[d,j]
__global__ __launch_bounds__(256) void bz_kernel(const float* __restrict__ bk,
    const float* __restrict__ WqT, float* __restrict__ bz)
{
    int j = blockIdx.x * 256 + threadIdx.x;
    float s = 0.f;
    for (int d = 0; d < 1024; d++) s = fmaf(bk[d], WqT[(size_t)d * 1024 + j], s);
    bz[j] = s;
}

__global__ void zero_f32(float* __restrict__ p, int n)
{
    int i = blockIdx.x * 256 + threadIdx.x;
    if (i < n) p[i] = 0.f;
}

// ---------------------------------------------------------------------------
// 3072-point complex FFT in LDS (3x1024 Stockham radix-2 + radix-3 combine)
// ---------------------------------------------------------------------------
__device__ __forceinline__ void fft3072(float* re0, float* im0, float* re1, float* im1,
                                        const float* twR, const float* twI,
                                        const float* t3R, const float* t3I, int tid)
{
    float* srcR = re0; float* srcI = im0;
    float* dstR = re1; float* dstI = im1;
    for (int s = 0; s < 10; s++) {
        int st = 1 << s;
        int m = 512 >> s;
        for (int w = tid; w < 1536; w += 256) {
            int sub = w >> 9, idx = w & 511;
            int p = idx >> s;
            int q = idx & (st - 1);
            int base = sub << 10;
            int ia = base + q + st * p;
            int ib = ia + st * m;
            float aR = srcR[ia], aI = srcI[ia];
            float bR = srcR[ib], bI = srcI[ib];
            int ti = p << s;
            float wR = twR[ti], wI = twI[ti];
            int io = base + q + st * 2 * p;
            dstR[io] = aR + bR; dstI[io] = aI + bI;
            float dR = aR - bR, dI = aI - bI;
            dstR[io + st] = dR * wR - dI * wI;
            dstI[io + st] = dR * wI + dI * wR;
        }
        __syncthreads();
        float* t;
        t = srcR; srcR = dstR; dstR = t;
        t = srcI; srcI = dstI; dstI = t;
    }
    const float OMR = -0.5f, OMI = -0.86602540378443864676f;
    for (int k2 = tid; k2 < 1024; k2 += 256) {
        float y0R = srcR[k2],        y0I = srcI[k2];
        float y1R = srcR[1024 + k2], y1I = srcI[1024 + k2];
        float y2R = srcR[2048 + k2], y2I = srcI[2048 + k2];
        float w1R = t3R[k2], w1I = t3I[k2];
        float w2R = w1R * w1R - w1I * w1I;
        float w2I = 2.f * w1R * w1I;
        float u1R = y1R * w1R - y1I * w1I, u1I = y1R * w1I + y1I * w1R;
        float u2R = y2R * w2R - y2I * w2I, u2I = y2R * w2I + y2I * w2R;
        dstR[k2] = y0R + u1R + u2R;
        dstI[k2] = y0I + u1I + u2I;
        dstR[1024 + k2] = y0R + (OMR * u1R - OMI * u1I) + (OMR * u2R + OMI * u2I);
        dstI[1024 + k2] = y0I + (OMR * u1I + OMI * u1R) + (OMR * u2I - OMI * u2R);
        dstR[2048 + k2] = y0R + (OMR * u1R + OMI * u1I) + (OMR * u2R - OMI * u2I);
        dstI[2048 + k2] = y0I + (OMR * u1I - OMI * u1R) + (OMR * u2I + OMI * u2R);
    }
    __syncthreads();
}

// ---------------------------------------------------------------------------
// Per (batch, 16-channel group): inputs channel-major [B, D, L] (coalesced!).
// Pack w = q + i*z, FFT, P[f] = Qf * conj(Zf), accumulate, atomicAdd into S.
// ---------------------------------------------------------------------------
__global__ __launch_bounds__(256) void fft_corr(const float* __restrict__ qT,
    const float* __restrict__ zT, float* __restrict__ S)
{
    __shared__ float re0[3072], im0[3072], re1[3072], im1[3072];
    __shared__ float twR[512], twI[512], t3R[1024], t3I[1024];
    const int tid = threadIdx.x;
    const int b = blockIdx.x >> 6;
    const int c0 = (blockIdx.x & 63) << 4;
    const float TWO_PI = 6.28318530717958647692f;
    for (int j = tid; j < 512; j += 256) {
        float s, c; sincosf(-TWO_PI * (float)j / 1024.f, &s, &c);
        twR[j] = c; twI[j] = s;
    }
    for (int j = tid; j < 1024; j += 256) {
        float s, c; sincosf(-TWO_PI * (float)j / 3072.f, &s, &c);
        t3R[j] = c; t3I[j] = s;
    }
    float pR[12], pI[12];
#pragma unroll
    for (int j = 0; j < 12; j++) { pR[j] = 0.f; pI[j] = 0.f; }
    __syncthreads();

    for (int ci = 0; ci < 16; ci++) {
        int c = c0 + ci;
        const float* qp = qT + ((size_t)b * DM + c) * LEN;
        const float* zp = zT + ((size_t)b * DM + c) * LEN;
        for (int t = tid; t < 3072; t += 256) {
            float qv = qp[t];
            float zv = zp[t];
            int t1 = t % 3, t2 = t / 3;
            re0[t1 * 1024 + t2] = qv;
            im0[t1 * 1024 + t2] = zv;
        }
        __syncthreads();
        fft3072(re0, im0, re1, im1, twR, twI, t3R, t3I, tid);
#pragma unroll
        for (int j = 0; j < 12; j++) {
            int f = tid + (j << 8);
            int fc = (f == 0) ? 0 : 3072 - f;
            float WfR = re1[f],  WfI = im1[f];
            float WcR = re1[fc], WcI = -im1[fc];
            float qR = 0.5f * (WfR + WcR), qI = 0.5f * (WfI + WcI);
            float dR = WfR - WcR, dI = WfI - WcI;
            float zR = 0.5f * dI, zI = -0.5f * dR;
            pR[j] += qR * zR + qI * zI;
            pI[j] += qI * zR - qR * zI;
        }
        __syncthreads();
    }
    float* Sb = S + (size_t)b * 3072 * 2;
#pragma unroll
    for (int j = 0; j < 12; j++) {
        int f = tid + (j << 8);
        atomicAdd(&Sb[f * 2 + 0], pR[j]);
        atomicAdd(&Sb[f * 2 + 1], pI[j]);
    }
}

__global__ __launch_bounds__(256) void ifft_mean(const float* __restrict__ S,
                                                 float* __restrict__ mv)
{
    __shared__ float re0[3072], im0[3072], re1[3072], im1[3072];
    __shared__ float twR[512], twI[512], t3R[1024], t3I[1024];
    const int tid = threadIdx.x;
    const int b = blockIdx.x;
    const float TWO_PI = 6.28318530717958647692f;
    for (int j = tid; j < 512; j += 256) {
        float s, c; sincosf(-TWO_PI * (float)j / 1024.f, &s, &c);
        twR[j] = c; twI[j] = s;
    }
    for (int j = tid; j < 1024; j += 256) {
        float s, c; sincosf(-TWO_PI * (float)j / 3072.f, &s, &c);
        t3R[j] = c; t3I[j] = s;
    }
    __syncthreads();
    for (int t = tid; t < 3072; t += 256) {
        float sR = S[((size_t)b * 3072 + t) * 2 + 0];
        float sI = S[((size_t)b * 3072 + t) * 2 + 1];
        int t1 = t % 3, t2 = t / 3;
        re0[t1 * 1024 + t2] = sR;
        im0[t1 * 1024 + t2] = -sI;
    }
    __syncthreads();
    fft3072(re0, im0, re1, im1, twR, twI, t3R, t3I, tid);
    const float scale = 1.f / (3072.f * 1024.f);
    for (int t = tid; t < 3072; t += 256)
        mv[(size_t)b * 3072 + t] = re1[t] * scale;
}

__global__ __launch_bounds__(256) void topk_softmax(const float* __restrict__ mv,
    float* __restrict__ wout, int* __restrict__ dout)
{
    const int b = blockIdx.x, tid = threadIdx.x;
    __shared__ float v[3072];
    __shared__ float rv[256];
    __shared__ int   ri[256];
    __shared__ float topv[TOPK];
    __shared__ int   topi[TOPK];
    for (int t = tid; t < 3072; t += 256) v[t] = mv[(size_t)b * 3072 + t];
    __syncthreads();
    for (int it = 0; it < TOPK; it++) {
        float best = -3.0e38f; int bi = 0;
        for (int t = tid; t < 3072; t += 256) {
            float x = v[t];
            if (x > best) { best = x; bi = t; }
        }
        rv[tid] = best; ri[tid] = bi;
        __syncthreads();
        for (int off = 128; off > 0; off >>= 1) {
            if (tid < off) {
                float ov = rv[tid + off]; int oi = ri[tid + off];
                if (ov > rv[tid] || (ov == rv[tid] && oi < ri[tid])) {
                    rv[tid] = ov; ri[tid] = oi;
                }
            }
            __syncthreads();
        }
        if (tid == 0) { topv[it] = rv[0]; topi[it] = ri[0]; v[ri[0]] = -3.0e38f; }
        __syncthreads();
    }
    if (tid == 0) {
        float m = topv[0];
        float e[TOPK]; float ssum = 0.f;
        for (int i = 0; i < TOPK; i++) { e[i] = expf(topv[i] - m); ssum += e[i]; }
        for (int i = 0; i < TOPK; i++) {
            wout[b * TOPK + i] = e[i] / ssum;
            dout[b * TOPK + i] = topi[i];
        }
    }
}

// agg[b,t,c] = sum_i w[b,i] * V[b,(t+d[b,i])%L,c]   (bf16 in, bf16 out)
__global__ __launch_bounds__(256) void agg_bf16(const unsigned short* __restrict__ V,
    const float* __restrict__ w, const int* __restrict__ d,
    unsigned short* __restrict__ agg)
{
    size_t gid = (size_t)blockIdx.x * 256 + threadIdx.x;   // 8-channel chunk index
    int c8 = (int)(gid & 127);
    size_t rest = gid >> 7;
    int t = (int)(rest % LEN);
    int b = (int)(rest / LEN);
    float acc[8];
#pragma unroll
    for (int j = 0; j < 8; j++) acc[j] = 0.f;
#pragma unroll
    for (int i = 0; i < TOPK; i++) {
        float wi = w[b * TOPK + i];
        int r = t + d[b * TOPK + i];
        if (r >= LEN) r -= LEN;
        const unsigned short* vp = V + ((size_t)b * LEN + r) * DM + c8 * 8;
        uint4 raw = *(const uint4*)vp;
        unsigned int uu[4] = {raw.x, raw.y, raw.z, raw.w};
#pragma unroll
        for (int k = 0; k < 4; k++) {
            acc[2 * k]     = fmaf(wi, bf2f((unsigned short)(uu[k] & 0xffff)), acc[2 * k]);
            acc[2 * k + 1] = fmaf(wi, bf2f((unsigned short)(uu[k] >> 16)), acc[2 * k + 1]);
        }
    }
    unsigned int ou[4];
#pragma unroll
    for (int k = 0; k < 4; k++)
        ou[k] = (unsigned int)f2bf(acc[2 * k]) | ((unsigned int)f2bf(acc[2 * k + 1]) << 16);
    uint4 o = {ou[0], ou[1], ou[2], ou[3]};
    *(uint4*)(agg + gid * 8) = o;
}

// ---------------------------------------------------------------------------
extern "C" void kernel_launch(void* const* d_in, const int* in_sizes, int n_in,
                              void* d_out, int out_size, void* d_ws, size_t ws_size,
                              hipStream_t stream)
{
    const float* queries = (const float*)d_in[0];
    const float* keys    = (const float*)d_in[1];
    const float* values  = (const float*)d_in[2];
    const float* Wq = (const float*)d_in[3];
    // bq: tau-constant in mean_value -> topk/softmax invariant; legally dropped
    const float* Wk = (const float*)d_in[5];
    const float* bk = (const float*)d_in[6];
    const float* Wv = (const float*)d_in[7];
    const float* bv = (const float*)d_in[8];
    const float* Wo = (const float*)d_in[9];
    const float* bo = (const float*)d_in[10];
    float* out = (float*)d_out;

    char* ws = (char*)d_ws;
    size_t off = 0;
    auto alloc = [&](size_t bytes) -> char* {
        char* p = ws + off;
        off += (bytes + 255) & ~(size_t)255;
        return p;
    };
    const size_t BLD = (size_t)BSZ * LEN * DM;          // 25165824 elements
    float* WqT  = (float*)alloc((size_t)1024 * 1024 * 4);
    float* Amat = (float*)alloc((size_t)1024 * 1024 * 4);
    float* bz   = (float*)alloc(1024 * 4);
    float* S    = (float*)alloc((size_t)BSZ * 3072 * 2 * 4);
    float* mv   = (float*)alloc((size_t)BSZ * 3072 * 4);
    float* wsm  = (float*)alloc(BSZ * TOPK * 4);
    int*   dly  = (int*)alloc(BSZ * TOPK * 4);
    unsigned short* WvT = (unsigned short*)alloc((size_t)1024 * 1024 * 2);
    unsigned short* WoT = (unsigned short*)alloc((size_t)1024 * 1024 * 2);
    // two big regions, phase-aliased:
    char* bigA = alloc(BLD * 4);   // phase1: qT f32   | phase2: vb16 + aggb (bf16)
    char* bigB = alloc(BLD * 4);   // phase1: zT f32   | phase2: Vb bf16
    float* qT = (float*)bigA;
    float* zT = (float*)bigB;
    unsigned short* vb16 = (unsigned short*)bigA;
    unsigned short* aggb = (unsigned short*)(bigA + BLD * 2);
    unsigned short* Vb   = (unsigned short*)bigB;

    const int BL = BSZ * LEN; // 24576

    // ---- selection path (f32) ----
    transpose_1024<<<1024, 256, 0, stream>>>(Wq, WqT);
    gemm_f32<<<dim3(8, 8), 256, 0, stream>>>(Wk, WqT, nullptr, Amat, 1024, 1024, 1024, 0);
    bz_kernel<<<4, 256, 0, stream>>>(bk, WqT, bz);
    // z^T directly: zT[b][c][t]
    gemm_f32<<<dim3(8, 192), 256, 0, stream>>>(keys, Amat, bz, zT, BL, 1024, 1024, 1);
    // q^T: [B,D,L]
    transpose_bld<<<dim3(32, 96, 8), 256, 0, stream>>>(queries, qT);
    zero_f32<<<(BSZ * 3072 * 2 + 255) / 256, 256, 0, stream>>>(S, BSZ * 3072 * 2);
    fft_corr<<<BSZ * 64, 256, 0, stream>>>(qT, zT, S);
    ifft_mean<<<BSZ, 256, 0, stream>>>(S, mv);
    topk_softmax<<<BSZ, 256, 0, stream>>>(mv, wsm, dly);

    // ---- value path (bf16 MFMA) ----
    conv_bf16<<<(int)((BLD / 4 + 255) / 256), 256, 0, stream>>>(values, vb16, BLD);
    transpose_w_bf16<<<1024, 256, 0, stream>>>(Wv, WvT);
    transpose_w_bf16<<<1024, 256, 0, stream>>>(Wo, WoT);
    gemm_bf16<<<dim3(8, 192), 256, 0, stream>>>(vb16, WvT, bv, Vb, BL, 1024, 1024, 1);
    agg_bf16<<<(int)(((size_t)BL * 128) / 256), 256, 0, stream>>>(Vb, wsm, dly, aggb);
    gemm_bf16<<<dim3(8, 192), 256, 0, stream>>>(aggb, WoT, bo, out, BL, 1024, 1024, 0);
}

// Round 3
// 1139.196 us; speedup vs baseline: 2.9649x; 1.3441x over previous
//
#include <hip/hip_runtime.h>
#include <math.h>

#define BSZ 8
#define LEN 3072
#define DM 1024
#define TOPK 8

typedef __attribute__((ext_vector_type(8))) short short8;
typedef __attribute__((ext_vector_type(4))) float f32x4;

__device__ __forceinline__ unsigned short f2bf(float x) {
    unsigned int u = __builtin_bit_cast(unsigned int, x);
    u += 0x7fffu + ((u >> 16) & 1u);   // RNE
    return (unsigned short)(u >> 16);
}
__device__ __forceinline__ float bf2f(unsigned short h) {
    unsigned int u = ((unsigned int)h) << 16;
    return __builtin_bit_cast(float, u);
}
__device__ __forceinline__ void gl_lds16(const void* g, void* l) {
    __builtin_amdgcn_global_load_lds(
        (const __attribute__((address_space(1))) unsigned int*)g,
        (__attribute__((address_space(3))) unsigned int*)l, 16, 0, 0);
}

// ---------------------------------------------------------------------------
// f32 tiled GEMM (only for the tiny 1024^3 Amat = Wk @ WqT product).
// ---------------------------------------------------------------------------
#define GBM 128
#define GBN 128
#define GBK 16

__global__ __launch_bounds__(256) void gemm_f32(const float* __restrict__ A,
    const float* __restrict__ B, float* __restrict__ C, int M, int N, int K)
{
    __shared__ float As[GBK][GBM];
    __shared__ float Bs[GBK][GBN];
    const int tid = threadIdx.x;
    const int tx = tid & 15, ty = tid >> 4;
    const size_t m0 = (size_t)blockIdx.y * GBM;
    const size_t n0 = (size_t)blockIdx.x * GBN;
    const int arow = tid >> 2, acol = (tid & 3) << 2;
    const int brow = tid >> 5, bcol = (tid & 31) << 2;

    float acc[8][8];
#pragma unroll
    for (int i = 0; i < 8; i++)
#pragma unroll
        for (int j = 0; j < 8; j++) acc[i][j] = 0.f;

    const float* Ap0 = A + (m0 + arow) * (size_t)K + acol;
    const float* Ap1 = A + (m0 + arow + 64) * (size_t)K + acol;
    const float* Bp0 = B + (size_t)brow * N + n0 + bcol;
    const float* Bp1 = B + (size_t)(brow + 8) * N + n0 + bcol;

    for (int k0 = 0; k0 < K; k0 += GBK) {
        float4 a0 = *(const float4*)(Ap0 + k0);
        float4 a1 = *(const float4*)(Ap1 + k0);
        float4 b0 = *(const float4*)(Bp0 + (size_t)k0 * N);
        float4 b1 = *(const float4*)(Bp1 + (size_t)k0 * N);
        __syncthreads();
        As[acol + 0][arow] = a0.x; As[acol + 1][arow] = a0.y;
        As[acol + 2][arow] = a0.z; As[acol + 3][arow] = a0.w;
        As[acol + 0][arow + 64] = a1.x; As[acol + 1][arow + 64] = a1.y;
        As[acol + 2][arow + 64] = a1.z; As[acol + 3][arow + 64] = a1.w;
        *(float4*)&Bs[brow][bcol] = b0;
        *(float4*)&Bs[brow + 8][bcol] = b1;
        __syncthreads();
#pragma unroll
        for (int kk = 0; kk < GBK; kk++) {
            float av[8], bv[8];
            *(float4*)&av[0] = *(const float4*)&As[kk][ty * 8];
            *(float4*)&av[4] = *(const float4*)&As[kk][ty * 8 + 4];
            *(float4*)&bv[0] = *(const float4*)&Bs[kk][tx * 8];
            *(float4*)&bv[4] = *(const float4*)&Bs[kk][tx * 8 + 4];
#pragma unroll
            for (int i = 0; i < 8; i++)
#pragma unroll
                for (int j = 0; j < 8; j++)
                    acc[i][j] = fmaf(av[i], bv[j], acc[i][j]);
        }
    }
#pragma unroll
    for (int i = 0; i < 8; i++) {
        size_t row = m0 + (size_t)(ty * 8 + i);
        float* Cp = C + row * N + n0 + tx * 8;
#pragma unroll
        for (int j = 0; j < 8; j++) Cp[j] = acc[i][j];
    }
}

// ---------------------------------------------------------------------------
// Split-bf16 MFMA GEMM for the selection-critical z path:
//   z = keys @ Amat + bz, computed as Khi@Ahi + Khi@Alo + Klo@Ahi
// (each split half bf16; ~17 effective mantissa bits; lo*lo term ~2^-18 dropped).
// Writes OUTPUT TRANSPOSED: zT[b][c][t], m = b*LEN + t.
// 128x128 tile, BK=32, 256 thr (2x2 waves), 16x16x32 MFMA, global_load_lds x16.
// ---------------------------------------------------------------------------
__global__ __launch_bounds__(256) void gemm_split_zT(
    const unsigned short* __restrict__ Khi, const unsigned short* __restrict__ Klo,
    const unsigned short* __restrict__ AhiT, const unsigned short* __restrict__ AloT,
    const float* __restrict__ bias, float* __restrict__ zT, int M, int N, int K)
{
    __shared__ unsigned short Ah[128 * 32];
    __shared__ unsigned short Al[128 * 32];
    __shared__ unsigned short Bh[128 * 32];
    __shared__ unsigned short Bl[128 * 32];
    const int tid = threadIdx.x;
    const int lane = tid & 63;
    const int wv = tid >> 6;
    const int wm = wv >> 1, wn = wv & 1;
    const int l16 = lane & 15, quad = lane >> 4;
    const size_t m0 = (size_t)blockIdx.y * 128;
    const size_t n0 = (size_t)blockIdx.x * 128;

    const int s0 = tid, s1 = tid + 256;       // segment: row = s>>2, col8 = s&3
    const size_t oA0 = (m0 + (s0 >> 2)) * (size_t)K + (s0 & 3) * 8;
    const size_t oA1 = (m0 + (s1 >> 2)) * (size_t)K + (s1 & 3) * 8;
    const size_t oB0 = (n0 + (s0 >> 2)) * (size_t)K + (s0 & 3) * 8;
    const size_t oB1 = (n0 + (s1 >> 2)) * (size_t)K + (s1 & 3) * 8;

    f32x4 acc[4][4];
#pragma unroll
    for (int i = 0; i < 4; i++)
#pragma unroll
        for (int j = 0; j < 4; j++) acc[i][j] = (f32x4){0.f, 0.f, 0.f, 0.f};

    for (int k0 = 0; k0 < K; k0 += 32) {
        __syncthreads();
        gl_lds16(Khi + oA0 + k0, &Ah[s0 * 8]);
        gl_lds16(Khi + oA1 + k0, &Ah[s1 * 8]);
        gl_lds16(Klo + oA0 + k0, &Al[s0 * 8]);
        gl_lds16(Klo + oA1 + k0, &Al[s1 * 8]);
        gl_lds16(AhiT + oB0 + k0, &Bh[s0 * 8]);
        gl_lds16(AhiT + oB1 + k0, &Bh[s1 * 8]);
        gl_lds16(AloT + oB0 + k0, &Bl[s0 * 8]);
        gl_lds16(AloT + oB1 + k0, &Bl[s1 * 8]);
        __syncthreads();
        short8 ah[4], al[4], bh[4], bl[4];
#pragma unroll
        for (int mi = 0; mi < 4; mi++) {
            int off = (wm * 64 + mi * 16 + l16) * 32 + quad * 8;
            ah[mi] = *(const short8*)&Ah[off];
            al[mi] = *(const short8*)&Al[off];
        }
#pragma unroll
        for (int ni = 0; ni < 4; ni++) {
            int off = (wn * 64 + ni * 16 + l16) * 32 + quad * 8;
            bh[ni] = *(const short8*)&Bh[off];
            bl[ni] = *(const short8*)&Bl[off];
        }
#pragma unroll
        for (int mi = 0; mi < 4; mi++)
#pragma unroll
            for (int ni = 0; ni < 4; ni++) {
                acc[mi][ni] = __builtin_amdgcn_mfma_f32_16x16x32_bf16(
                    ah[mi], bh[ni], acc[mi][ni], 0, 0, 0);
                acc[mi][ni] = __builtin_amdgcn_mfma_f32_16x16x32_bf16(
                    ah[mi], bl[ni], acc[mi][ni], 0, 0, 0);
                acc[mi][ni] = __builtin_amdgcn_mfma_f32_16x16x32_bf16(
                    al[mi], bh[ni], acc[mi][ni], 0, 0, 0);
            }
    }

    const int b = (int)(m0 / LEN);
    const int t0 = (int)(m0 % LEN);
#pragma unroll
    for (int mi = 0; mi < 4; mi++) {
#pragma unroll
        for (int ni = 0; ni < 4; ni++) {
            int c = (int)n0 + wn * 64 + ni * 16 + l16;
            int t = t0 + wm * 64 + mi * 16 + quad * 4;
            float bb = bias[c];
            float* zp = zT + ((size_t)b * DM + c) * LEN + t;
#pragma unroll
            for (int r = 0; r < 4; r++) zp[r] = acc[mi][ni][r] + bb;
        }
    }
}

// ---------------------------------------------------------------------------
// bf16 MFMA GEMM (m97 structure): C[M,N] = A[M,K] * Bt[N,K]^T + bias.
// cmode: 0 -> f32 C, 1 -> bf16 C.
// ---------------------------------------------------------------------------
__global__ __launch_bounds__(256) void gemm_bf16(const unsigned short* __restrict__ A,
    const unsigned short* __restrict__ Bt, const float* __restrict__ bias,
    void* __restrict__ C, int M, int N, int K, int cmode)
{
    __shared__ unsigned short As[128 * 32];
    __shared__ unsigned short Bs[128 * 32];
    const int tid = threadIdx.x;
    const int lane = tid & 63;
    const int wv = tid >> 6;
    const int wm = wv >> 1, wn = wv & 1;
    const int l16 = lane & 15, quad = lane >> 4;
    const size_t m0 = (size_t)blockIdx.y * 128;
    const size_t n0 = (size_t)blockIdx.x * 128;

    const int s0 = tid, s1 = tid + 256;
    const unsigned short* gA0 = A + (m0 + (s0 >> 2)) * (size_t)K + (s0 & 3) * 8;
    const unsigned short* gA1 = A + (m0 + (s1 >> 2)) * (size_t)K + (s1 & 3) * 8;
    const unsigned short* gB0 = Bt + (n0 + (s0 >> 2)) * (size_t)K + (s0 & 3) * 8;
    const unsigned short* gB1 = Bt + (n0 + (s1 >> 2)) * (size_t)K + (s1 & 3) * 8;
    unsigned short* lA0 = &As[s0 * 8];
    unsigned short* lA1 = &As[s1 * 8];
    unsigned short* lB0 = &Bs[s0 * 8];
    unsigned short* lB1 = &Bs[s1 * 8];

    f32x4 acc[4][4];
#pragma unroll
    for (int i = 0; i < 4; i++)
#pragma unroll
        for (int j = 0; j < 4; j++) acc[i][j] = (f32x4){0.f, 0.f, 0.f, 0.f};

    for (int k0 = 0; k0 < K; k0 += 32) {
        __syncthreads();
        gl_lds16(gA0 + k0, lA0);
        gl_lds16(gA1 + k0, lA1);
        gl_lds16(gB0 + k0, lB0);
        gl_lds16(gB1 + k0, lB1);
        __syncthreads();
        short8 af[4], bf[4];
#pragma unroll
        for (int mi = 0; mi < 4; mi++)
            af[mi] = *(const short8*)&As[(wm * 64 + mi * 16 + l16) * 32 + quad * 8];
#pragma unroll
        for (int ni = 0; ni < 4; ni++)
            bf[ni] = *(const short8*)&Bs[(wn * 64 + ni * 16 + l16) * 32 + quad * 8];
#pragma unroll
        for (int mi = 0; mi < 4; mi++)
#pragma unroll
            for (int ni = 0; ni < 4; ni++)
                acc[mi][ni] = __builtin_amdgcn_mfma_f32_16x16x32_bf16(
                    af[mi], bf[ni], acc[mi][ni], 0, 0, 0);
    }

#pragma unroll
    for (int mi = 0; mi < 4; mi++) {
#pragma unroll
        for (int ni = 0; ni < 4; ni++) {
            int gm = (int)m0 + wm * 64 + mi * 16 + quad * 4;
            int gn = (int)n0 + wn * 64 + ni * 16 + l16;
            float bb = bias ? bias[gn] : 0.f;
#pragma unroll
            for (int r = 0; r < 4; r++) {
                float v = acc[mi][ni][r] + bb;
                if (cmode == 0)
                    ((float*)C)[(size_t)(gm + r) * N + gn] = v;
                else
                    ((unsigned short*)C)[(size_t)(gm + r) * N + gn] = f2bf(v);
            }
        }
    }
}

// ---------------------------------------------------------------------------
// [B, L, D] f32 -> [B, D, L] f32 transpose (queries)
// ---------------------------------------------------------------------------
__global__ __launch_bounds__(256) void transpose_bld(const float* __restrict__ in,
                                                     float* __restrict__ out)
{
    __shared__ float tile[32][33];
    int b = blockIdx.z;
    int d0 = blockIdx.x * 32, t0 = blockIdx.y * 32;
    int tx = threadIdx.x & 31, ty = threadIdx.x >> 5;
    const float* ip = in + (size_t)b * LEN * DM;
    float* op = out + (size_t)b * DM * LEN;
#pragma unroll
    for (int r = 0; r < 4; r++)
        tile[ty * 4 + r][tx] = ip[(size_t)(t0 + ty * 4 + r) * DM + d0 + tx];
    __syncthreads();
#pragma unroll
    for (int r = 0; r < 4; r++)
        op[(size_t)(d0 + ty * 4 + r) * LEN + t0 + tx] = tile[tx][ty * 4 + r];
}

// 1024x1024 f32 transpose (Wq -> WqT)
__global__ __launch_bounds__(256) void transpose_1024(const float* __restrict__ in,
                                                      float* __restrict__ out)
{
    __shared__ float tile[32][33];
    int bx = blockIdx.x & 31, by = blockIdx.x >> 5;
    int tx = threadIdx.x & 31, tq = threadIdx.x >> 5;
#pragma unroll
    for (int r = 0; r < 4; r++)
        tile[tq * 4 + r][tx] = in[(size_t)(by * 32 + tq * 4 + r) * 1024 + bx * 32 + tx];
    __syncthreads();
#pragma unroll
    for (int r = 0; r < 4; r++)
        out[(size_t)(bx * 32 + tq * 4 + r) * 1024 + by * 32 + tx] = tile[tx][tq * 4 + r];
}

// 1024x1024 f32 W[K][N] -> bf16 WT[N][K]
__global__ __launch_bounds__(256) void transpose_w_bf16(const float* __restrict__ in,
                                                        unsigned short* __restrict__ out)
{
    __shared__ float tile[32][33];
    int bx = blockIdx.x & 31, by = blockIdx.x >> 5;
    int tx = threadIdx.x & 31, tq = threadIdx.x >> 5;
#pragma unroll
    for (int r = 0; r < 4; r++)
        tile[tq * 4 + r][tx] = in[(size_t)(by * 32 + tq * 4 + r) * 1024 + bx * 32 + tx];
    __syncthreads();
#pragma unroll
    for (int r = 0; r < 4; r++)
        out[(size_t)(bx * 32 + tq * 4 + r) * 1024 + by * 32 + tx] = f2bf(tile[tx][tq * 4 + r]);
}

// 1024x1024 f32 W[K][N] -> split bf16 hi/lo, transposed [N][K]
__global__ __launch_bounds__(256) void transpose_w_split(const float* __restrict__ in,
    unsigned short* __restrict__ hi, unsigned short* __restrict__ lo)
{
    __shared__ float tile[32][33];
    int bx = blockIdx.x & 31, by = blockIdx.x >> 5;
    int tx = threadIdx.x & 31, tq = threadIdx.x >> 5;
#pragma unroll
    for (int r = 0; r < 4; r++)
        tile[tq * 4 + r][tx] = in[(size_t)(by * 32 + tq * 4 + r) * 1024 + bx * 32 + tx];
    __syncthreads();
#pragma unroll
    for (int r = 0; r < 4; r++) {
        float x = tile[tx][tq * 4 + r];
        unsigned short h = f2bf(x);
        unsigned short l = f2bf(x - bf2f(h));
        size_t o = (size_t)(bx * 32 + tq * 4 + r) * 1024 + by * 32 + tx;
        hi[o] = h; lo[o] = l;
    }
}

// f32 -> split bf16 hi/lo elementwise (n multiple of 4)
__global__ __launch_bounds__(256) void split_bf16(const float* __restrict__ in,
    unsigned short* __restrict__ hi, unsigned short* __restrict__ lo, size_t n)
{
    size_t i = ((size_t)blockIdx.x * 256 + threadIdx.x) * 4;
    if (i >= n) return;
    float4 v = *(const float4*)(in + i);
    ushort4 h, l;
    h.x = f2bf(v.x); l.x = f2bf(v.x - bf2f(h.x));
    h.y = f2bf(v.y); l.y = f2bf(v.y - bf2f(h.y));
    h.z = f2bf(v.z); l.z = f2bf(v.z - bf2f(h.z));
    h.w = f2bf(v.w); l.w = f2bf(v.w - bf2f(h.w));
    *(ushort4*)(hi + i) = h;
    *(ushort4*)(lo + i) = l;
}

// f32 -> bf16 elementwise (n multiple of 4)
__global__ __launch_bounds__(256) void conv_bf16(const float* __restrict__ in,
                                                 unsigned short* __restrict__ out, size_t n)
{
    size_t i = ((size_t)blockIdx.x * 256 + threadIdx.x) * 4;
    if (i >= n) return;
    float4 v = *(const float4*)(in + i);
    ushort4 o;
    o.x = f2bf(v.x); o.y = f2bf(v.y); o.z = f2bf(v.z); o.w = f2bf(v.w);
    *(ushort4*)(out + i) = o;
}

// bz[j] = sum_d bk[d] * WqT[d,j]
__global__ __launch_bounds__(256) void bz_kernel(const float* __restrict__ bk,
    const float* __restrict__ WqT, float* __restrict__ bz)
{
    int j = blockIdx.x * 256 + threadIdx.x;
    float s = 0.f;
    for (int d = 0; d < 1024; d++) s = fmaf(bk[d], WqT[(size_t)d * 1024 + j], s);
    bz[j] = s;
}

__global__ void zero_f32(float* __restrict__ p, int n)
{
    int i = blockIdx.x * 256 + threadIdx.x;
    if (i < n) p[i] = 0.f;
}

// ---------------------------------------------------------------------------
// 3072-point complex FFT in LDS (3x1024 Stockham radix-2 + radix-3 combine)
// ---------------------------------------------------------------------------
__device__ __forceinline__ void fft3072(float* re0, float* im0, float* re1, float* im1,
                                        const float* twR, const float* twI,
                                        const float* t3R, const float* t3I, int tid)
{
    float* srcR = re0; float* srcI = im0;
    float* dstR = re1; float* dstI = im1;
    for (int s = 0; s < 10; s++) {
        int st = 1 << s;
        int m = 512 >> s;
        for (int w = tid; w < 1536; w += 256) {
            int sub = w >> 9, idx = w & 511;
            int p = idx >> s;
            int q = idx & (st - 1);
            int base = sub << 10;
            int ia = base + q + st * p;
            int ib = ia + st * m;
            float aR = srcR[ia], aI = srcI[ia];
            float bR = srcR[ib], bI = srcI[ib];
            int ti = p << s;
            float wR = twR[ti], wI = twI[ti];
            int io = base + q + st * 2 * p;
            dstR[io] = aR + bR; dstI[io] = aI + bI;
            float dR = aR - bR, dI = aI - bI;
            dstR[io + st] = dR * wR - dI * wI;
            dstI[io + st] = dR * wI + dI * wR;
        }
        __syncthreads();
        float* t;
        t = srcR; srcR = dstR; dstR = t;
        t = srcI; srcI = dstI; dstI = t;
    }
    const float OMR = -0.5f, OMI = -0.86602540378443864676f;
    for (int k2 = tid; k2 < 1024; k2 += 256) {
        float y0R = srcR[k2],        y0I = srcI[k2];
        float y1R = srcR[1024 + k2], y1I = srcI[1024 + k2];
        float y2R = srcR[2048 + k2], y2I = srcI[2048 + k2];
        float w1R = t3R[k2], w1I = t3I[k2];
        float w2R = w1R * w1R - w1I * w1I;
        float w2I = 2.f * w1R * w1I;
        float u1R = y1R * w1R - y1I * w1I, u1I = y1R * w1I + y1I * w1R;
        float u2R = y2R * w2R - y2I * w2I, u2I = y2R * w2I + y2I * w2R;
        dstR[k2] = y0R + u1R + u2R;
        dstI[k2] = y0I + u1I + u2I;
        dstR[1024 + k2] = y0R + (OMR * u1R - OMI * u1I) + (OMR * u2R + OMI * u2I);
        dstI[1024 + k2] = y0I + (OMR * u1I + OMI * u1R) + (OMR * u2I - OMI * u2R);
        dstR[2048 + k2] = y0R + (OMR * u1R + OMI * u1I) + (OMR * u2R - OMI * u2I);
        dstI[2048 + k2] = y0I + (OMR * u1I - OMI * u1R) + (OMR * u2I + OMI * u2R);
    }
    __syncthreads();
}

// ---------------------------------------------------------------------------
// Per (batch, 16-channel group): inputs channel-major [B, D, L] (coalesced).
// Pack w = q + i*z, FFT, P[f] = Qf * conj(Zf), accumulate, atomicAdd into S.
// ---------------------------------------------------------------------------
__global__ __launch_bounds__(256) void fft_corr(const float* __restrict__ qT,
    const float* __restrict__ zT, float* __restrict__ S)
{
    __shared__ float re0[3072], im0[3072], re1[3072], im1[3072];
    __shared__ float twR[512], twI[512], t3R[1024], t3I[1024];
    const int tid = threadIdx.x;
    const int b = blockIdx.x >> 6;
    const int c0 = (blockIdx.x & 63) << 4;
    const float TWO_PI = 6.28318530717958647692f;
    for (int j = tid; j < 512; j += 256) {
        float s, c; sincosf(-TWO_PI * (float)j / 1024.f, &s, &c);
        twR[j] = c; twI[j] = s;
    }
    for (int j = tid; j < 1024; j += 256) {
        float s, c; sincosf(-TWO_PI * (float)j / 3072.f, &s, &c);
        t3R[j] = c; t3I[j] = s;
    }
    float pR[12], pI[12];
#pragma unroll
    for (int j = 0; j < 12; j++) { pR[j] = 0.f; pI[j] = 0.f; }
    __syncthreads();

    for (int ci = 0; ci < 16; ci++) {
        int c = c0 + ci;
        const float* qp = qT + ((size_t)b * DM + c) * LEN;
        const float* zp = zT + ((size_t)b * DM + c) * LEN;
        for (int t = tid; t < 3072; t += 256) {
            float qv = qp[t];
            float zv = zp[t];
            int t1 = t % 3, t2 = t / 3;
            re0[t1 * 1024 + t2] = qv;
            im0[t1 * 1024 + t2] = zv;
        }
        __syncthreads();
        fft3072(re0, im0, re1, im1, twR, twI, t3R, t3I, tid);
#pragma unroll
        for (int j = 0; j < 12; j++) {
            int f = tid + (j << 8);
            int fc = (f == 0) ? 0 : 3072 - f;
            float WfR = re1[f],  WfI = im1[f];
            float WcR = re1[fc], WcI = -im1[fc];
            float qR = 0.5f * (WfR + WcR), qI = 0.5f * (WfI + WcI);
            float dR = WfR - WcR, dI = WfI - WcI;
            float zR = 0.5f * dI, zI = -0.5f * dR;
            pR[j] += qR * zR + qI * zI;
            pI[j] += qI * zR - qR * zI;
        }
        __syncthreads();
    }
    float* Sb = S + (size_t)b * 3072 * 2;
#pragma unroll
    for (int j = 0; j < 12; j++) {
        int f = tid + (j << 8);
        atomicAdd(&Sb[f * 2 + 0], pR[j]);
        atomicAdd(&Sb[f * 2 + 1], pI[j]);
    }
}

__global__ __launch_bounds__(256) void ifft_mean(const float* __restrict__ S,
                                                 float* __restrict__ mv)
{
    __shared__ float re0[3072], im0[3072], re1[3072], im1[3072];
    __shared__ float twR[512], twI[512], t3R[1024], t3I[1024];
    const int tid = threadIdx.x;
    const int b = blockIdx.x;
    const float TWO_PI = 6.28318530717958647692f;
    for (int j = tid; j < 512; j += 256) {
        float s, c; sincosf(-TWO_PI * (float)j / 1024.f, &s, &c);
        twR[j] = c; twI[j] = s;
    }
    for (int j = tid; j < 1024; j += 256) {
        float s, c; sincosf(-TWO_PI * (float)j / 3072.f, &s, &c);
        t3R[j] = c; t3I[j] = s;
    }
    __syncthreads();
    for (int t = tid; t < 3072; t += 256) {
        float sR = S[((size_t)b * 3072 + t) * 2 + 0];
        float sI = S[((size_t)b * 3072 + t) * 2 + 1];
        int t1 = t % 3, t2 = t / 3;
        re0[t1 * 1024 + t2] = sR;
        im0[t1 * 1024 + t2] = -sI;
    }
    __syncthreads();
    fft3072(re0, im0, re1, im1, twR, twI, t3R, t3I, tid);
    const float scale = 1.f / (3072.f * 1024.f);
    for (int t = tid; t < 3072; t += 256)
        mv[(size_t)b * 3072 + t] = re1[t] * scale;
}

__global__ __launch_bounds__(256) void topk_softmax(const float* __restrict__ mv,
    float* __restrict__ wout, int* __restrict__ dout)
{
    const int b = blockIdx.x, tid = threadIdx.x;
    __shared__ float v[3072];
    __shared__ float rv[256];
    __shared__ int   ri[256];
    __shared__ float topv[TOPK];
    __shared__ int   topi[TOPK];
    for (int t = tid; t < 3072; t += 256) v[t] = mv[(size_t)b * 3072 + t];
    __syncthreads();
    for (int it = 0; it < TOPK; it++) {
        float best = -3.0e38f; int bi = 0;
        for (int t = tid; t < 3072; t += 256) {
            float x = v[t];
            if (x > best) { best = x; bi = t; }
        }
        rv[tid] = best; ri[tid] = bi;
        __syncthreads();
        for (int off = 128; off > 0; off >>= 1) {
            if (tid < off) {
                float ov = rv[tid + off]; int oi = ri[tid + off];
                if (ov > rv[tid] || (ov == rv[tid] && oi < ri[tid])) {
                    rv[tid] = ov; ri[tid] = oi;
                }
            }
            __syncthreads();
        }
        if (tid == 0) { topv[it] = rv[0]; topi[it] = ri[0]; v[ri[0]] = -3.0e38f; }
        __syncthreads();
    }
    if (tid == 0) {
        float m = topv[0];
        float e[TOPK]; float ssum = 0.f;
        for (int i = 0; i < TOPK; i++) { e[i] = expf(topv[i] - m); ssum += e[i]; }
        for (int i = 0; i < TOPK; i++) {
            wout[b * TOPK + i] = e[i] / ssum;
            dout[b * TOPK + i] = topi[i];
        }
    }
}

// agg[b,t,c] = sum_i w[b,i] * V[b,(t+d[b,i])%L,c]   (bf16 in, bf16 out)
__global__ __launch_bounds__(256) void agg_bf16(const unsigned short* __restrict__ V,
    const float* __restrict__ w, const int* __restrict__ d,
    unsigned short* __restrict__ agg)
{
    size_t gid = (size_t)blockIdx.x * 256 + threadIdx.x;   // 8-channel chunk index
    int c8 = (int)(gid & 127);
    size_t rest = gid >> 7;
    int t = (int)(rest % LEN);
    int b = (int)(rest / LEN);
    float acc[8];
#pragma unroll
    for (int j = 0; j < 8; j++) acc[j] = 0.f;
#pragma unroll
    for (int i = 0; i < TOPK; i++) {
        float wi = w[b * TOPK + i];
        int r = t + d[b * TOPK + i];
        if (r >= LEN) r -= LEN;
        const unsigned short* vp = V + ((size_t)b * LEN + r) * DM + c8 * 8;
        uint4 raw = *(const uint4*)vp;
        unsigned int uu[4] = {raw.x, raw.y, raw.z, raw.w};
#pragma unroll
        for (int k = 0; k < 4; k++) {
            acc[2 * k]     = fmaf(wi, bf2f((unsigned short)(uu[k] & 0xffff)), acc[2 * k]);
            acc[2 * k + 1] = fmaf(wi, bf2f((unsigned short)(uu[k] >> 16)), acc[2 * k + 1]);
        }
    }
    unsigned int ou[4];
#pragma unroll
    for (int k = 0; k < 4; k++)
        ou[k] = (unsigned int)f2bf(acc[2 * k]) | ((unsigned int)f2bf(acc[2 * k + 1]) << 16);
    uint4 o = {ou[0], ou[1], ou[2], ou[3]};
    *(uint4*)(agg + gid * 8) = o;
}

// ---------------------------------------------------------------------------
extern "C" void kernel_launch(void* const* d_in, const int* in_sizes, int n_in,
                              void* d_out, int out_size, void* d_ws, size_t ws_size,
                              hipStream_t stream)
{
    const float* queries = (const float*)d_in[0];
    const float* keys    = (const float*)d_in[1];
    const float* values  = (const float*)d_in[2];
    const float* Wq = (const float*)d_in[3];
    // bq: tau-constant in mean_value -> topk/softmax invariant; legally dropped
    const float* Wk = (const float*)d_in[5];
    const float* bk = (const float*)d_in[6];
    const float* Wv = (const float*)d_in[7];
    const float* bv = (const float*)d_in[8];
    const float* Wo = (const float*)d_in[9];
    const float* bo = (const float*)d_in[10];
    float* out = (float*)d_out;

    char* ws = (char*)d_ws;
    size_t off = 0;
    auto alloc = [&](size_t bytes) -> char* {
        char* p = ws + off;
        off += (bytes + 255) & ~(size_t)255;
        return p;
    };
    const size_t BLD = (size_t)BSZ * LEN * DM;          // 25165824 elements
    float* WqT  = (float*)alloc((size_t)1024 * 1024 * 4);
    float* Amat = (float*)alloc((size_t)1024 * 1024 * 4);
    unsigned short* AhiT = (unsigned short*)alloc((size_t)1024 * 1024 * 2);
    unsigned short* AloT = (unsigned short*)alloc((size_t)1024 * 1024 * 2);
    float* bz   = (float*)alloc(1024 * 4);
    float* S    = (float*)alloc((size_t)BSZ * 3072 * 2 * 4);
    float* mv   = (float*)alloc((size_t)BSZ * 3072 * 4);
    float* wsm  = (float*)alloc(BSZ * TOPK * 4);
    int*   dly  = (int*)alloc(BSZ * TOPK * 4);
    unsigned short* WvT = (unsigned short*)alloc((size_t)1024 * 1024 * 2);
    unsigned short* WoT = (unsigned short*)alloc((size_t)1024 * 1024 * 2);
    // two big regions, phase-aliased:
    //   bigA: ph0: khi+klo (bf16) | ph1: qT f32 | ph2: vb16 + aggb (bf16)
    //   bigB: ph1: zT f32         | ph2: Vb bf16
    char* bigA = alloc(BLD * 4);
    char* bigB = alloc(BLD * 4);
    unsigned short* khi = (unsigned short*)bigA;
    unsigned short* klo = (unsigned short*)(bigA + BLD * 2);
    float* qT = (float*)bigA;
    float* zT = (float*)bigB;
    unsigned short* vb16 = (unsigned short*)bigA;
    unsigned short* aggb = (unsigned short*)(bigA + BLD * 2);
    unsigned short* Vb   = (unsigned short*)bigB;

    const int BL = BSZ * LEN; // 24576

    // ---- selection path (split-bf16 MFMA; ~17 mantissa bits) ----
    transpose_1024<<<1024, 256, 0, stream>>>(Wq, WqT);
    gemm_f32<<<dim3(8, 8), 256, 0, stream>>>(Wk, WqT, Amat, 1024, 1024, 1024);
    bz_kernel<<<4, 256, 0, stream>>>(bk, WqT, bz);
    transpose_w_split<<<1024, 256, 0, stream>>>(Amat, AhiT, AloT);
    split_bf16<<<(int)((BLD / 4 + 255) / 256), 256, 0, stream>>>(keys, khi, klo, BLD);
    // zT[b][c][t] = (keys @ Amat + bz)^T  via 3-product split-bf16 MFMA
    gemm_split_zT<<<dim3(8, 192), 256, 0, stream>>>(khi, klo, AhiT, AloT, bz, zT,
                                                    BL, 1024, 1024);
    // qT[b][c][t]  (khi/klo dead now; overwrite bigA)
    transpose_bld<<<dim3(32, 96, 8), 256, 0, stream>>>(queries, qT);
    zero_f32<<<(BSZ * 3072 * 2 + 255) / 256, 256, 0, stream>>>(S, BSZ * 3072 * 2);
    fft_corr<<<BSZ * 64, 256, 0, stream>>>(qT, zT, S);
    ifft_mean<<<BSZ, 256, 0, stream>>>(S, mv);
    topk_softmax<<<BSZ, 256, 0, stream>>>(mv, wsm, dly);

    // ---- value path (bf16 MFMA) ----
    conv_bf16<<<(int)((BLD / 4 + 255) / 256), 256, 0, stream>>>(values, vb16, BLD);
    transpose_w_bf16<<<1024, 256, 0, stream>>>(Wv, WvT);
    transpose_w_bf16<<<1024, 256, 0, stream>>>(Wo, WoT);
    gemm_bf16<<<dim3(8, 192), 256, 0, stream>>>(vb16, WvT, bv, Vb, BL, 1024, 1024, 1);
    agg_bf16<<<(int)(((size_t)BL * 128) / 256), 256, 0, stream>>>(Vb, wsm, dly, aggb);
    gemm_bf16<<<dim3(8, 192), 256, 0, stream>>>(aggb, WoT, bo, out, BL, 1024, 1024, 0);
}